// Round 1
// baseline (259.679 us; speedup 1.0000x reference)
//
#include <hip/hip_runtime.h>
#include <hip/hip_bf16.h>
#include <math.h>

#define B_ 32
#define T_ 2000
#define DE_ 512
#define DD_ 1024
#define A_ 128
#define FN_ 32
#define FS_ 16
#define KW_ (2*FS_+1)   // 33

typedef __bf16 bf16x8 __attribute__((ext_vector_type(8)));
typedef __bf16 bf16x4 __attribute__((ext_vector_type(4)));
typedef float f32x4 __attribute__((ext_vector_type(4)));

#define BT 64            // t-rows per score block
#define LSTR 40          // loc tile LDS stride (bf16)

// ---------------------------------------------------------------------------
// Kernel 1: prep.
//  blocks   0..63 : enc_w/att_w fp32->bf16
//  blocks  64..191: pdec[b][a] = att_b[a] + input_dec[b] . dec_w[a]
//  blocks 192..208: zero ctx_un (16384 f) + denom (32 f)
// ---------------------------------------------------------------------------
__global__ __launch_bounds__(256) void prep_kernel(
    const float* __restrict__ enc_w, const float* __restrict__ att_w,
    const float* __restrict__ input_dec, const float* __restrict__ dec_w,
    const float* __restrict__ att_b,
    __bf16* __restrict__ enc_bf, __bf16* __restrict__ att_bf,
    float* __restrict__ pdec, float* __restrict__ ctx_un /* denom follows */)
{
    int bx = blockIdx.x, tid = threadIdx.x;
    if (bx < 64) {
        int i = bx * 256 + tid;                         // float4 index
        float4 v = ((const float4*)enc_w)[i];
        bf16x4 o;
        o[0] = (__bf16)v.x; o[1] = (__bf16)v.y; o[2] = (__bf16)v.z; o[3] = (__bf16)v.w;
        *(bf16x4*)(enc_bf + (size_t)i * 4) = o;
        if (i < (A_ * FN_) / 4) {
            float4 w = ((const float4*)att_w)[i];
            bf16x4 p;
            p[0] = (__bf16)w.x; p[1] = (__bf16)w.y; p[2] = (__bf16)w.z; p[3] = (__bf16)w.w;
            *(bf16x4*)(att_bf + (size_t)i * 4) = p;
        }
    } else if (bx < 192) {
        int pb = bx - 64;                               // 0..127
        int b  = pb >> 2;
        int a0 = (pb & 3) * 32;
        int al = tid >> 3;                              // 0..31
        int kg = tid & 7;                               // 0..7
        int a  = a0 + al;
        const float4* w = (const float4*)(dec_w + (size_t)a * DD_);
        const float4* x = (const float4*)(input_dec + (size_t)b * DD_);
        float acc = 0.f;
        #pragma unroll 8
        for (int j = 0; j < 32; j++) {
            int i4 = kg + j * 8;
            float4 wv = w[i4], xv = x[i4];
            acc += wv.x * xv.x + wv.y * xv.y + wv.z * xv.z + wv.w * xv.w;
        }
        acc += __shfl_xor(acc, 1, 64);
        acc += __shfl_xor(acc, 2, 64);
        acc += __shfl_xor(acc, 4, 64);
        if (kg == 0) pdec[b * A_ + a] = acc + att_b[a];
    } else {
        int idx = (bx - 192) * 256 + tid;               // float4 index
        if (idx < (B_ * DE_ + B_) / 4 + 1)              // 16416 floats -> 4104 f4
            ((float4*)ctx_un)[idx] = make_float4(0.f, 0.f, 0.f, 0.f);
    }
}

// ---------------------------------------------------------------------------
// Kernel 2: score + context partials. One block = (b, 64 t-rows).
// B (enc_bf, 128x512 bf16 = 131 KB) is read DIRECTLY from global: it is the
// same weight matrix for every block, fully L1/L2-resident, so LDS staging
// (and its 16 per-block barrier drains) was pure overhead. K-loop is now
// barrier-free: pure global loads + MFMA, compiler software-pipelines.
// Max-free softmax: w = exp(score - M), M = sum|out_w| (data-independent
// upper bound, identical in every block). Block then accumulates its own
// 64x512 tile (L2-hot) into ctx_un via atomics, and sum(w) into denom.
// ---------------------------------------------------------------------------
__global__ __launch_bounds__(256, 4) void score_kernel(
    const float* __restrict__ input_enc, const __bf16* __restrict__ enc_bf,
    const float* __restrict__ prev_att,  const float* __restrict__ conv_w,
    const __bf16* __restrict__ att_bf,   const float* __restrict__ pdec,
    const float* __restrict__ out_w,     const int* __restrict__ lengths,
    float* __restrict__ wbuf, float* __restrict__ ctx_un,
    float* __restrict__ denom)
{
    __shared__ float pa_s[BT + 2 * FS_];
    __shared__ float cw_s[KW_ * FN_];
    __shared__ __align__(16) __bf16 loc_s[BT * LSTR];
    __shared__ float w_s[BT];

    const int tid = threadIdx.x;
    const int b  = blockIdx.y;
    const int t0 = blockIdx.x * BT;
    const int len = lengths[b];

    for (int j = tid; j < BT + 2 * FS_; j += 256) {
        int t = t0 - FS_ + j;
        pa_s[j] = (t >= 0 && t < T_) ? prev_att[b * T_ + t] : 0.f;
    }
    for (int idx = tid; idx < FN_ * KW_; idx += 256) {
        int f = idx / KW_, k = idx % KW_;
        cw_s[k * FN_ + f] = conv_w[idx];
    }
    __syncthreads();

    {   // conv -> loc (bf16)
        int f = tid & 31, r0 = tid >> 5;
        for (int r = r0; r < BT; r += 8) {
            float acc = 0.f;
            #pragma unroll
            for (int k = 0; k < KW_; k++) acc += pa_s[r + k] * cw_s[k * FN_ + f];
            loc_s[r * LSTR + f] = (__bf16)acc;
        }
    }
    __syncthreads();

    const int lane = tid & 63;
    const int wv   = tid >> 6;
    const int col  = lane & 15;
    const int grp  = lane >> 4;
    const int rowb = wv * 16 + col;
    const int t_row = t0 + rowb;
    const int t_clamp = t_row < T_ ? t_row : T_ - 1;

    f32x4 acc[8];
    const f32x4 zero = (f32x4){0.f, 0.f, 0.f, 0.f};

    {   // loc-projection MFMA (K=32=FN)
        bf16x8 afrag = *(const bf16x8*)(loc_s + rowb * LSTR + grp * 8);
        #pragma unroll
        for (int i = 0; i < 8; i++) {
            bf16x8 bfrag = *(const bf16x8*)(att_bf + (size_t)(i * 16 + col) * FN_ + grp * 8);
            acc[i] = __builtin_amdgcn_mfma_f32_16x16x32_bf16(afrag, bfrag, zero, 0, 0, 0);
        }
    }

    const float* arow = input_enc + ((size_t)(b * T_ + t_clamp)) * DE_ + grp * 8;

    // per-MFMA B row base pointers (all loops fully unrolled -> registers)
    const __bf16* brow[8];
    #pragma unroll
    for (int i = 0; i < 8; i++)
        brow[i] = enc_bf + (size_t)(i * 16 + col) * DE_ + grp * 8;

    #pragma unroll
    for (int kc = 0; kc < DE_; kc += 64) {
        float4 a00 = *(const float4*)(arow + kc);
        float4 a01 = *(const float4*)(arow + kc + 4);
        float4 a10 = *(const float4*)(arow + kc + 32);
        float4 a11 = *(const float4*)(arow + kc + 36);

        bf16x8 af;
        af[0] = (__bf16)a00.x; af[1] = (__bf16)a00.y;
        af[2] = (__bf16)a00.z; af[3] = (__bf16)a00.w;
        af[4] = (__bf16)a01.x; af[5] = (__bf16)a01.y;
        af[6] = (__bf16)a01.z; af[7] = (__bf16)a01.w;
        #pragma unroll
        for (int i = 0; i < 8; i++) {
            bf16x8 bfrag = *(const bf16x8*)(brow[i] + kc);
            acc[i] = __builtin_amdgcn_mfma_f32_16x16x32_bf16(af, bfrag, acc[i], 0, 0, 0);
        }
        af[0] = (__bf16)a10.x; af[1] = (__bf16)a10.y;
        af[2] = (__bf16)a10.z; af[3] = (__bf16)a10.w;
        af[4] = (__bf16)a11.x; af[5] = (__bf16)a11.y;
        af[6] = (__bf16)a11.z; af[7] = (__bf16)a11.w;
        #pragma unroll
        for (int i = 0; i < 8; i++) {
            bf16x8 bfrag = *(const bf16x8*)(brow[i] + kc + 32);
            acc[i] = __builtin_amdgcn_mfma_f32_16x16x32_bf16(af, bfrag, acc[i], 0, 0, 0);
        }
    }

    // epilogue: s = tanh(acc + bias) . out_w over a; M = sum|out_w|
    float s[4] = {0.f, 0.f, 0.f, 0.f};
    float Mabs = 0.f;
    #pragma unroll
    for (int i = 0; i < 8; i++) {
        int a = i * 16 + col;
        float ow = out_w[a];
        Mabs += fabsf(ow);
        float bias = pdec[b * A_ + a];
        #pragma unroll
        for (int r = 0; r < 4; r++) {
            float v = acc[i][r] + bias;
            v = fminf(fmaxf(v, -15.f), 15.f);
            float e = __expf(2.f * v);
            s[r] += ow * ((e - 1.f) / (e + 1.f));
        }
    }
    #pragma unroll
    for (int r = 0; r < 4; r++) {
        s[r] += __shfl_xor(s[r], 1, 64);
        s[r] += __shfl_xor(s[r], 2, 64);
        s[r] += __shfl_xor(s[r], 4, 64);
        s[r] += __shfl_xor(s[r], 8, 64);
    }
    Mabs += __shfl_xor(Mabs, 1, 64);
    Mabs += __shfl_xor(Mabs, 2, 64);
    Mabs += __shfl_xor(Mabs, 4, 64);
    Mabs += __shfl_xor(Mabs, 8, 64);    // same value & rounding in every wave

    if (col == 0) {
        #pragma unroll
        for (int r = 0; r < 4; r++) {
            int rl = wv * 16 + grp * 4 + r;
            int t = t0 + rl;
            float w = 0.f;
            if (t < len) w = __expf(s[r] - Mabs);
            w_s[rl] = w;
            if (t < T_) wbuf[b * T_ + t] = w;
        }
    }
    __syncthreads();

    // denominator partial (wave 0)
    if (tid < 64) {
        float w = w_s[tid];
        w += __shfl_xor(w, 1, 64);
        w += __shfl_xor(w, 2, 64);
        w += __shfl_xor(w, 4, 64);
        w += __shfl_xor(w, 8, 64);
        w += __shfl_xor(w, 16, 64);
        w += __shfl_xor(w, 32, 64);
        if (tid == 0) atomicAdd(&denom[b], w);
    }

    // context partial: tile rows are L2-hot from the GEMM reads
    int n_eff = len - t0;
    if (n_eff > BT) n_eff = BT;
    if (n_eff > 0) {
        int d0 = tid * 2;
        const float* ebase = input_enc + ((size_t)(b * T_ + t0)) * DE_ + d0;
        float cx = 0.f, cy = 0.f;
        #pragma unroll 8
        for (int t = 0; t < n_eff; t++) {
            float w = w_s[t];
            float2 v = *(const float2*)(ebase + (size_t)t * DE_);
            cx += w * v.x;
            cy += w * v.y;
        }
        atomicAdd(&ctx_un[b * DE_ + d0 + 0], cx);
        atomicAdd(&ctx_un[b * DE_ + d0 + 1], cy);
    }
}

// ---------------------------------------------------------------------------
// Kernel 3: finalize. blocks 0..63: att = wbuf/denom; 64..79: ctx = ctx_un/denom
// ---------------------------------------------------------------------------
__global__ __launch_bounds__(256) void finalize_kernel(
    const float* __restrict__ wbuf, const float* __restrict__ ctx_un,
    const float* __restrict__ denom, float* __restrict__ out)
{
    int bx = blockIdx.x, tid = threadIdx.x;
    if (bx < 64) {
        int i4 = bx * 256 + tid;
        if (i4 < (B_ * T_) / 4) {
            int b = i4 / (T_ / 4);
            float inv = 1.f / denom[b];
            float4 w = ((const float4*)wbuf)[i4];
            w.x *= inv; w.y *= inv; w.z *= inv; w.w *= inv;
            ((float4*)(out + B_ * DE_))[i4] = w;
        }
    } else {
        int j = (bx - 64) * 256 + tid;          // 0..4095
        int b = j / (DE_ / 4);
        float inv = 1.f / denom[b];
        float4 c = ((const float4*)ctx_un)[j];
        c.x *= inv; c.y *= inv; c.z *= inv; c.w *= inv;
        ((float4*)out)[j] = c;
    }
}

// ---------------------------------------------------------------------------
extern "C" void kernel_launch(void* const* d_in, const int* in_sizes, int n_in,
                              void* d_out, int out_size, void* d_ws, size_t ws_size,
                              hipStream_t stream)
{
    const float* input_enc   = (const float*)d_in[0];
    const int*   enc_lengths = (const int*)d_in[1];
    const float* input_dec   = (const float*)d_in[2];
    const float* prev_att    = (const float*)d_in[3];
    const float* conv_w      = (const float*)d_in[4];
    const float* enc_w       = (const float*)d_in[5];
    const float* dec_w       = (const float*)d_in[6];
    const float* att_w       = (const float*)d_in[7];
    const float* att_b       = (const float*)d_in[8];
    const float* out_w       = (const float*)d_in[9];

    float* out = (float*)d_out;                 // [0:B*DE) context, [B*DE:) att_weight
    char* ws = (char*)d_ws;
    float*  pdec   = (float*)ws;                              // 4096 f   (16384 B)
    float*  wbuf   = (float*)(ws + 16384);                    // 64000 f  (256000 B)
    __bf16* enc_bf = (__bf16*)(ws + 272384);                  // A*DE bf16 (131072 B)
    __bf16* att_bf = (__bf16*)(ws + 403456);                  // A*FN bf16 (8192 B)
    float*  ctx_un = (float*)(ws + 411648);                   // 16384 f  (65536 B)
    float*  denom  = (float*)(ws + 477184);                   // 32 f

    prep_kernel<<<209, 256, 0, stream>>>(enc_w, att_w, input_dec, dec_w, att_b,
                                         enc_bf, att_bf, pdec, ctx_un);

    dim3 sgrid((T_ + BT - 1) / BT, B_);
    score_kernel<<<sgrid, 256, 0, stream>>>(input_enc, enc_bf, prev_att, conv_w,
                                            att_bf, pdec, out_w, enc_lengths,
                                            wbuf, ctx_un, denom);

    finalize_kernel<<<80, 256, 0, stream>>>(wbuf, ctx_un, denom, out);
}

// Round 2
// 232.410 us; speedup vs baseline: 1.1173x; 1.1173x over previous
//
#include <hip/hip_runtime.h>
#include <hip/hip_bf16.h>
#include <math.h>

#define B_ 32
#define T_ 2000
#define DE_ 512
#define DD_ 1024
#define A_ 128
#define FN_ 32
#define FS_ 16
#define KW_ (2*FS_+1)   // 33

typedef __bf16 bf16x8 __attribute__((ext_vector_type(8)));
typedef __bf16 bf16x4 __attribute__((ext_vector_type(4)));
typedef float f32x4 __attribute__((ext_vector_type(4)));

#define BT 64            // t-rows per score block
#define LSTR 40          // loc tile LDS stride (bf16)

// async global->LDS, 16 B per lane; dest = lds base (wave-uniform) + lane*16
__device__ __forceinline__ void load_lds16(const void* g, void* l) {
    __builtin_amdgcn_global_load_lds(
        (const __attribute__((address_space(1))) unsigned int*)g,
        (__attribute__((address_space(3))) unsigned int*)l, 16, 0, 0);
}

// ---------------------------------------------------------------------------
// Kernel 1: prep.
//  blocks   0..63 : enc_w/att_w fp32->bf16
//  blocks  64..191: pdec[b][a] = att_b[a] + input_dec[b] . dec_w[a]
//  blocks 192..208: zero ctx_un (16384 f) + denom (32 f)
// ---------------------------------------------------------------------------
__global__ __launch_bounds__(256) void prep_kernel(
    const float* __restrict__ enc_w, const float* __restrict__ att_w,
    const float* __restrict__ input_dec, const float* __restrict__ dec_w,
    const float* __restrict__ att_b,
    __bf16* __restrict__ enc_bf, __bf16* __restrict__ att_bf,
    float* __restrict__ pdec, float* __restrict__ ctx_un /* denom follows */)
{
    int bx = blockIdx.x, tid = threadIdx.x;
    if (bx < 64) {
        int i = bx * 256 + tid;                         // float4 index
        float4 v = ((const float4*)enc_w)[i];
        bf16x4 o;
        o[0] = (__bf16)v.x; o[1] = (__bf16)v.y; o[2] = (__bf16)v.z; o[3] = (__bf16)v.w;
        *(bf16x4*)(enc_bf + (size_t)i * 4) = o;
        if (i < (A_ * FN_) / 4) {
            float4 w = ((const float4*)att_w)[i];
            bf16x4 p;
            p[0] = (__bf16)w.x; p[1] = (__bf16)w.y; p[2] = (__bf16)w.z; p[3] = (__bf16)w.w;
            *(bf16x4*)(att_bf + (size_t)i * 4) = p;
        }
    } else if (bx < 192) {
        int pb = bx - 64;                               // 0..127
        int b  = pb >> 2;
        int a0 = (pb & 3) * 32;
        int al = tid >> 3;                              // 0..31
        int kg = tid & 7;                               // 0..7
        int a  = a0 + al;
        const float4* w = (const float4*)(dec_w + (size_t)a * DD_);
        const float4* x = (const float4*)(input_dec + (size_t)b * DD_);
        float acc = 0.f;
        #pragma unroll 8
        for (int j = 0; j < 32; j++) {
            int i4 = kg + j * 8;
            float4 wv = w[i4], xv = x[i4];
            acc += wv.x * xv.x + wv.y * xv.y + wv.z * xv.z + wv.w * xv.w;
        }
        acc += __shfl_xor(acc, 1, 64);
        acc += __shfl_xor(acc, 2, 64);
        acc += __shfl_xor(acc, 4, 64);
        if (kg == 0) pdec[b * A_ + a] = acc + att_b[a];
    } else {
        int idx = (bx - 192) * 256 + tid;               // float4 index
        if (idx < (B_ * DE_ + B_) / 4 + 1)              // 16416 floats -> 4104 f4
            ((float4*)ctx_un)[idx] = make_float4(0.f, 0.f, 0.f, 0.f);
    }
}

// ---------------------------------------------------------------------------
// Kernel 2: score + context partials. One block = (b, 64 t-rows).
// B (enc_bf) double-buffered in LDS (T3-minimum 2-phase): next chunk's
// global_load_lds issued BEFORE this chunk's MFMAs; one __syncthreads per
// iter (its vmcnt(0) is the counted drain, stage latency hides under
// ds_read+MFMA). A rows prefetched one iter ahead in registers.
// Conv is register-blocked: 40 pa floats + 33 cw floats in regs, 264 FMA
// with compile-time indices -> ~8x fewer LDS ops than the ds-read-per-MAC
// version; cw read direct from global (4 KB, L1-hot), cw_s LDS deleted.
// Max-free softmax: w = exp(score - M), M = sum|out_w| (data-independent
// upper bound, identical in every block). Block then accumulates its own
// 64x512 tile (L2-hot) into ctx_un via atomics, and sum(w) into denom.
// ---------------------------------------------------------------------------
__global__ __launch_bounds__(256, 4) void score_kernel(
    const float* __restrict__ input_enc, const __bf16* __restrict__ enc_bf,
    const float* __restrict__ prev_att,  const float* __restrict__ conv_w,
    const __bf16* __restrict__ att_bf,   const float* __restrict__ pdec,
    const float* __restrict__ out_w,     const int* __restrict__ lengths,
    float* __restrict__ wbuf, float* __restrict__ ctx_un,
    float* __restrict__ denom)
{
    __shared__ __align__(16) char Bt[2][16384];  // B chunk dbuf: 128 rows x 64 k bf16
    __shared__ __align__(16) float pa_s[BT + 2 * FS_];
    __shared__ __align__(16) __bf16 loc_s[BT * LSTR];
    __shared__ float w_s[BT];

    const int tid = threadIdx.x;
    const int b  = blockIdx.y;
    const int t0 = blockIdx.x * BT;
    const int len = lengths[b];

    // conv weights for this thread's filter f: direct from global (L1-hot)
    const int f    = tid & 31;
    const int rblk = tid >> 5;                   // 0..7 -> rows rblk*8..rblk*8+7
    float cwr[KW_];
    #pragma unroll
    for (int k = 0; k < KW_; k++) cwr[k] = conv_w[f * KW_ + k];

    for (int j = tid; j < BT + 2 * FS_; j += 256) {
        int t = t0 - FS_ + j;
        pa_s[j] = (t >= 0 && t < T_) ? prev_att[b * T_ + t] : 0.f;
    }
    __syncthreads();

    {   // conv -> loc (bf16), register-blocked: 8 consecutive rows per thread
        float par[40];
        #pragma unroll
        for (int j = 0; j < 10; j++)
            *(float4*)&par[j * 4] = *(const float4*)&pa_s[rblk * 8 + j * 4];
        float accv[8] = {0.f, 0.f, 0.f, 0.f, 0.f, 0.f, 0.f, 0.f};
        #pragma unroll
        for (int k = 0; k < KW_; k++) {
            float c = cwr[k];
            #pragma unroll
            for (int j = 0; j < 8; j++) accv[j] += par[j + k] * c;
        }
        #pragma unroll
        for (int j = 0; j < 8; j++)
            loc_s[(rblk * 8 + j) * LSTR + f] = (__bf16)accv[j];
    }
    __syncthreads();

    const int lane = tid & 63;
    const int wv   = tid >> 6;
    const int col  = lane & 15;
    const int grp  = lane >> 4;
    const int rowb = wv * 16 + col;
    const int t_row = t0 + rowb;
    const int t_clamp = t_row < T_ ? t_row : T_ - 1;
    const int sw = (col & 7);                    // XOR swizzle key for ds reads

    // ---- prologue: stage buf0 (kc=0); hide its latency under loc-proj MFMA
    #pragma unroll
    for (int j = 0; j < 4; j++) {
        int s  = j * 256 + tid;
        int r  = s >> 3;
        int cp = s & 7;
        int c  = cp ^ (r & 7);
        load_lds16(enc_bf + (size_t)r * DE_ + c * 8,
                   Bt[0] + j * 4096 + wv * 1024);
    }

    f32x4 acc[8];
    const f32x4 zero = (f32x4){0.f, 0.f, 0.f, 0.f};

    {   // loc-projection MFMA (K=32=FN)
        bf16x8 afrag = *(const bf16x8*)(loc_s + rowb * LSTR + grp * 8);
        #pragma unroll
        for (int i = 0; i < 8; i++) {
            bf16x8 bfrag = *(const bf16x8*)(att_bf + (size_t)(i * 16 + col) * FN_ + grp * 8);
            acc[i] = __builtin_amdgcn_mfma_f32_16x16x32_bf16(afrag, bfrag, zero, 0, 0, 0);
        }
    }

    const float* arow = input_enc + ((size_t)(b * T_ + t_clamp)) * DE_ + grp * 8;

    // preload A for iter 0
    float4 a00 = *(const float4*)(arow + 0);
    float4 a01 = *(const float4*)(arow + 4);
    float4 a10 = *(const float4*)(arow + 32);
    float4 a11 = *(const float4*)(arow + 36);

    __syncthreads();                             // buf0 staged (vmcnt(0)+barrier)

    int cur = 0;
    #pragma unroll
    for (int it = 0; it < 8; ++it) {
        const int kc = it * 64;
        float4 n00, n01, n10, n11;
        if (it < 7) {
            // stage next B chunk into the other buffer (issue-early)
            #pragma unroll
            for (int j = 0; j < 4; j++) {
                int s  = j * 256 + tid;
                int r  = s >> 3;
                int cp = s & 7;
                int c  = cp ^ (r & 7);
                load_lds16(enc_bf + (size_t)r * DE_ + (kc + 64) + c * 8,
                           Bt[cur ^ 1] + j * 4096 + wv * 1024);
            }
            // prefetch next A
            n00 = *(const float4*)(arow + kc + 64);
            n01 = *(const float4*)(arow + kc + 68);
            n10 = *(const float4*)(arow + kc + 96);
            n11 = *(const float4*)(arow + kc + 100);
        }

        bf16x8 af;
        af[0] = (__bf16)a00.x; af[1] = (__bf16)a00.y;
        af[2] = (__bf16)a00.z; af[3] = (__bf16)a00.w;
        af[4] = (__bf16)a01.x; af[5] = (__bf16)a01.y;
        af[6] = (__bf16)a01.z; af[7] = (__bf16)a01.w;
        #pragma unroll
        for (int i = 0; i < 8; i++) {
            bf16x8 bfrag = *(const bf16x8*)(Bt[cur] + (i * 16 + col) * 128 + ((grp ^ sw) * 16));
            acc[i] = __builtin_amdgcn_mfma_f32_16x16x32_bf16(af, bfrag, acc[i], 0, 0, 0);
        }
        af[0] = (__bf16)a10.x; af[1] = (__bf16)a10.y;
        af[2] = (__bf16)a10.z; af[3] = (__bf16)a10.w;
        af[4] = (__bf16)a11.x; af[5] = (__bf16)a11.y;
        af[6] = (__bf16)a11.z; af[7] = (__bf16)a11.w;
        #pragma unroll
        for (int i = 0; i < 8; i++) {
            bf16x8 bfrag = *(const bf16x8*)(Bt[cur] + (i * 16 + col) * 128 + (((4 + grp) ^ sw) * 16));
            acc[i] = __builtin_amdgcn_mfma_f32_16x16x32_bf16(af, bfrag, acc[i], 0, 0, 0);
        }

        __syncthreads();       // vmcnt(0)+lgkmcnt(0)+barrier: next buf + A ready
        if (it < 7) { a00 = n00; a01 = n01; a10 = n10; a11 = n11; }
        cur ^= 1;
    }

    // epilogue: s = tanh(acc + bias) . out_w over a; M = sum|out_w|
    float s[4] = {0.f, 0.f, 0.f, 0.f};
    float Mabs = 0.f;
    #pragma unroll
    for (int i = 0; i < 8; i++) {
        int a = i * 16 + col;
        float ow = out_w[a];
        Mabs += fabsf(ow);
        float bias = pdec[b * A_ + a];
        #pragma unroll
        for (int r = 0; r < 4; r++) {
            float v = acc[i][r] + bias;
            v = fminf(fmaxf(v, -15.f), 15.f);
            float e = __expf(2.f * v);
            s[r] += ow * ((e - 1.f) / (e + 1.f));
        }
    }
    #pragma unroll
    for (int r = 0; r < 4; r++) {
        s[r] += __shfl_xor(s[r], 1, 64);
        s[r] += __shfl_xor(s[r], 2, 64);
        s[r] += __shfl_xor(s[r], 4, 64);
        s[r] += __shfl_xor(s[r], 8, 64);
    }
    Mabs += __shfl_xor(Mabs, 1, 64);
    Mabs += __shfl_xor(Mabs, 2, 64);
    Mabs += __shfl_xor(Mabs, 4, 64);
    Mabs += __shfl_xor(Mabs, 8, 64);    // same value & rounding in every wave

    if (col == 0) {
        #pragma unroll
        for (int r = 0; r < 4; r++) {
            int rl = wv * 16 + grp * 4 + r;
            int t = t0 + rl;
            float w = 0.f;
            if (t < len) w = __expf(s[r] - Mabs);
            w_s[rl] = w;
            if (t < T_) wbuf[b * T_ + t] = w;
        }
    }
    __syncthreads();

    // denominator partial (wave 0)
    if (tid < 64) {
        float w = w_s[tid];
        w += __shfl_xor(w, 1, 64);
        w += __shfl_xor(w, 2, 64);
        w += __shfl_xor(w, 4, 64);
        w += __shfl_xor(w, 8, 64);
        w += __shfl_xor(w, 16, 64);
        w += __shfl_xor(w, 32, 64);
        if (tid == 0) atomicAdd(&denom[b], w);
    }

    // context partial: tile rows are L2-hot from the GEMM reads
    int n_eff = len - t0;
    if (n_eff > BT) n_eff = BT;
    if (n_eff > 0) {
        int d0 = tid * 2;
        const float* ebase = input_enc + ((size_t)(b * T_ + t0)) * DE_ + d0;
        float cx = 0.f, cy = 0.f;
        #pragma unroll 8
        for (int t = 0; t < n_eff; t++) {
            float w = w_s[t];
            float2 v = *(const float2*)(ebase + (size_t)t * DE_);
            cx += w * v.x;
            cy += w * v.y;
        }
        atomicAdd(&ctx_un[b * DE_ + d0 + 0], cx);
        atomicAdd(&ctx_un[b * DE_ + d0 + 1], cy);
    }
}

// ---------------------------------------------------------------------------
// Kernel 3: finalize. blocks 0..63: att = wbuf/denom; 64..79: ctx = ctx_un/denom
// ---------------------------------------------------------------------------
__global__ __launch_bounds__(256) void finalize_kernel(
    const float* __restrict__ wbuf, const float* __restrict__ ctx_un,
    const float* __restrict__ denom, float* __restrict__ out)
{
    int bx = blockIdx.x, tid = threadIdx.x;
    if (bx < 64) {
        int i4 = bx * 256 + tid;
        if (i4 < (B_ * T_) / 4) {
            int b = i4 / (T_ / 4);
            float inv = 1.f / denom[b];
            float4 w = ((const float4*)wbuf)[i4];
            w.x *= inv; w.y *= inv; w.z *= inv; w.w *= inv;
            ((float4*)(out + B_ * DE_))[i4] = w;
        }
    } else {
        int j = (bx - 64) * 256 + tid;          // 0..4095
        int b = j / (DE_ / 4);
        float inv = 1.f / denom[b];
        float4 c = ((const float4*)ctx_un)[j];
        c.x *= inv; c.y *= inv; c.z *= inv; c.w *= inv;
        ((float4*)out)[j] = c;
    }
}

// ---------------------------------------------------------------------------
extern "C" void kernel_launch(void* const* d_in, const int* in_sizes, int n_in,
                              void* d_out, int out_size, void* d_ws, size_t ws_size,
                              hipStream_t stream)
{
    const float* input_enc   = (const float*)d_in[0];
    const int*   enc_lengths = (const int*)d_in[1];
    const float* input_dec   = (const float*)d_in[2];
    const float* prev_att    = (const float*)d_in[3];
    const float* conv_w      = (const float*)d_in[4];
    const float* enc_w       = (const float*)d_in[5];
    const float* dec_w       = (const float*)d_in[6];
    const float* att_w       = (const float*)d_in[7];
    const float* att_b       = (const float*)d_in[8];
    const float* out_w       = (const float*)d_in[9];

    float* out = (float*)d_out;                 // [0:B*DE) context, [B*DE:) att_weight
    char* ws = (char*)d_ws;
    float*  pdec   = (float*)ws;                              // 4096 f   (16384 B)
    float*  wbuf   = (float*)(ws + 16384);                    // 64000 f  (256000 B)
    __bf16* enc_bf = (__bf16*)(ws + 272384);                  // A*DE bf16 (131072 B)
    __bf16* att_bf = (__bf16*)(ws + 403456);                  // A*FN bf16 (8192 B)
    float*  ctx_un = (float*)(ws + 411648);                   // 16384 f  (65536 B)
    float*  denom  = (float*)(ws + 477184);                   // 32 f

    prep_kernel<<<209, 256, 0, stream>>>(enc_w, att_w, input_dec, dec_w, att_b,
                                         enc_bf, att_bf, pdec, ctx_un);

    dim3 sgrid((T_ + BT - 1) / BT, B_);
    score_kernel<<<sgrid, 256, 0, stream>>>(input_enc, enc_bf, prev_att, conv_w,
                                            att_bf, pdec, out_w, enc_lengths,
                                            wbuf, ctx_un, denom);

    finalize_kernel<<<80, 256, 0, stream>>>(wbuf, ctx_un, denom, out);
}